// Round 8
// baseline (481.067 us; speedup 1.0000x reference)
//
#include <hip/hip_runtime.h>
#include <cstddef>

#define BB    16
#define NN    2048
#define BN    (BB * NN)
#define TPB   1024
#define SPLIT 16                 // blocks per batch
#define TILE  128                // NN / SPLIT rows (cols) owned per block
#define GRIDB (BB * SPLIT)       // 256 blocks = 1 per CU
#define EPSF  1e-9f
#define CTRPAD 64                // ints per counter slot (256B)
#define NBAR  20

typedef float f2 __attribute__((ext_vector_type(2)));

__device__ __forceinline__ float fast_exp2(float x) {
#if __has_builtin(__builtin_amdgcn_exp2f)
    return __builtin_amdgcn_exp2f(x);
#else
    return exp2f(x);
#endif
}
__device__ __forceinline__ float sysload(const float* p) {
    return __hip_atomic_load(p, __ATOMIC_RELAXED, __HIP_MEMORY_SCOPE_SYSTEM);
}
__device__ __forceinline__ void sysstore(float* p, float v) {
    __hip_atomic_store(p, v, __ATOMIC_RELAXED, __HIP_MEMORY_SCOPE_SYSTEM);
}

// per-batch barrier: 16 arrivals, use-once counter, leader-only bounded spin.
// No __threadfence: all cross-block data is device-scope atomics / system-scope
// loads+stores, so no L2 writeback is needed (R5's 826MB-FETCH failure mode).
__device__ __forceinline__ void bbar(int* c) {
    __syncthreads();                       // drains each wave's vmcnt first
    if (threadIdx.x == 0) {
        __hip_atomic_fetch_add(c, 1, __ATOMIC_ACQ_REL, __HIP_MEMORY_SCOPE_SYSTEM);
        int spins = 0;
        while (__hip_atomic_load(c, __ATOMIC_RELAXED, __HIP_MEMORY_SCOPE_SYSTEM) < SPLIT) {
#if __has_builtin(__builtin_amdgcn_s_sleep)
            __builtin_amdgcn_s_sleep(8);
#endif
            if (++spins > (1 << 20)) break;   // no-hang safety valve
        }
    }
    __syncthreads();
}

// pack (x,y,z,|v|^2) per point
__global__ void prep(const float* __restrict__ preds, const float* __restrict__ labels,
                     float4* __restrict__ Prow, float4* __restrict__ Lcol) {
    int i = blockIdx.x * 256 + threadIdx.x;
    const float* p = preds + (size_t)i * 3;
    float x = p[0], y = p[1], z = p[2];
    Prow[i] = make_float4(x, y, z, x * x + y * y + z * z);
    const float* l = labels + (size_t)i * 3;
    float a = l[0], c = l[1], d = l[2];
    Lcol[i] = make_float4(a, c, d, a * a + c * c + d * d);
}

__global__ __launch_bounds__(TPB, 4) void emd_all(
    const float4* __restrict__ Prow, const float4* __restrict__ Lcol,
    float* __restrict__ S, float* __restrict__ T,
    float* __restrict__ RS, float* __restrict__ RR,
    float* __restrict__ AUX, int* __restrict__ ctr,
    float4* __restrict__ st4, float* __restrict__ st1,
    float* __restrict__ out)
{
    __shared__ float s_red[2];
    const int blk = blockIdx.x, split = blk & (SPLIT - 1), b = blk >> 4;
    const int t = threadIdx.x;
    const int base = b * NN, i0 = base + split * TILE;
    const int sb = blk * TILE;               // block-private staging slice

    // per-thread data held all 10 rounds: 2 cols + 2 rows (raw)
    float4 L0 = Lcol[base + t], L1 = Lcol[base + t + TPB];
    float4 P0 = Prow[base + t], P1 = Prow[base + t + TPB];
    float4 Pr = make_float4(0, 0, 0, 0), Lc = make_float4(0, 0, 0, 0);
    float cur = 1.f, cost = 1.f, outacc = 0.f;
    if (t < TILE) { Pr = Prow[i0 + t]; Lc = Lcol[i0 + t]; }

    const float LOG2E = 1.44269504088896f;
    int bar = 0;
    for (int k = 0; k < 9; k++) {
        const float ef = (k < 8) ? -(float)(1 << (14 - 2 * k)) : -0.25f;
        const float c1 = ef * LOG2E, invc1 = 1.f / c1, n2 = -2.f * c1;

        // =============== phase A: col sums S,T ===============
        if (t < TILE) {
            int idx = i0 + t;
            if (k > 0) {                     // combB(k-1) for owned rows
                float rs = sysload(RS + idx), rr = sysload(RR + idx);
                sysstore(RS + idx, 0.f); sysstore(RR + idx, 0.f);
                outacc += cur * rr;          // round k-1 result term
                cur = fmaxf(cur * (1.f - rs), 0.f);
            }
            st4[sb + t] = make_float4(Pr.x, Pr.y, Pr.z, c1 * Pr.w);
            st1[sb + t] = cur;
        }
        f2 gx = {n2 * L0.x, n2 * L1.x}, gy = {n2 * L0.y, n2 * L1.y};
        f2 gz = {n2 * L0.z, n2 * L1.z}, am = {c1 * L0.w, c1 * L1.w};
        f2 Sa = {0.f, 0.f}, Ta = {0.f, 0.f};
        __syncthreads();
#pragma unroll 4
        for (int j = 0; j < TILE; j++) {
            float4 q = st4[sb + j];          // uniform, L1-hot, no LDS
            float cu = st1[sb + j];
            f2 arg = q.x * gx + (q.y * gy + (q.z * gz + (am + q.w)));
            f2 e; e.x = fast_exp2(arg.x); e.y = fast_exp2(arg.y);
            Sa += e;
            Ta += e * cu;
        }
        atomicAdd(S + base + t, Sa.x); atomicAdd(S + base + t + TPB, Sa.y);
        atomicAdd(T + base + t, Ta.x); atomicAdd(T + base + t + TPB, Ta.y);
        bbar(ctr + (size_t)(bar * BB + b) * CTRPAD); bar++;

        // =============== phase B: row sums RS,RR ===============
        if (t < TILE) {                      // combA for owned cols
            int idx = i0 + t;
            float Sv = sysload(S + idx), Tv = sysload(T + idx);
            sysstore(S + idx, 0.f); sysstore(T + idx, 0.f);   // ready for A_{k+1}
            float D1 = fmaf(cost, Sv, EPSF);
            float S2 = cost * Tv / D1;
            float bw = fminf(cost / (S2 + EPSF), 1.f);
            float cc = cost * bw / D1;
            cost = fmaxf(fmaf(-S2, bw, cost), 0.f);
            st4[sb + t] = make_float4(Lc.x, Lc.y, Lc.z, c1 * Lc.w);
            st1[sb + t] = cc;
        }
        f2 hx = {n2 * P0.x, n2 * P1.x}, hy = {n2 * P0.y, n2 * P1.y};
        f2 hz = {n2 * P0.z, n2 * P1.z}, hn = {c1 * P0.w, c1 * P1.w};
        f2 RSa = {0.f, 0.f}, RRa = {0.f, 0.f};
        __syncthreads();
#pragma unroll 4
        for (int j = 0; j < TILE; j++) {
            float4 q = st4[sb + j];
            float ccj = st1[sb + j];
            f2 arg = q.x * hx + (q.y * hy + (q.z * hz + (hn + q.w)));
            f2 e; e.x = fast_exp2(arg.x); e.y = fast_exp2(arg.y);
            f2 w = e * ccj;
            RSa += w;
            RRa += w * arg;                  // sum w*arg; *1/c1 at store
        }
        atomicAdd(RS + base + t, RSa.x); atomicAdd(RS + base + t + TPB, RSa.y);
        atomicAdd(RR + base + t, RRa.x * invc1);
        atomicAdd(RR + base + t + TPB, RRa.y * invc1);
        bbar(ctr + (size_t)(bar * BB + b) * CTRPAD); bar++;
    }

    // ====== round 9 (ef=0 -> e==1): closed rank-1 form ======
    // (i) cur9 + term8 + T9 = sum(cur9)
    if (t < TILE) {
        int idx = i0 + t;
        float rs = sysload(RS + idx), rr = sysload(RR + idx);
        outacc += cur * rr;                  // round 8 result term
        cur = fmaxf(cur * (1.f - rs), 0.f);  // cur9
        float s = cur;
#pragma unroll
        for (int o = 32; o > 0; o >>= 1) s += __shfl_down(s, o, 64);
        if ((t & 63) == 0) atomicAdd(AUX + b * 8 + 0, s);
    }
    bbar(ctr + (size_t)(bar * BB + b) * CTRPAD); bar++;
    // (ii) cc9 per owned col -> A=sum cc9, B=sum cc9*|l|^2, C=sum cc9*l
    if (t < TILE) {
        float T9 = sysload(AUX + b * 8 + 0);
        float D1 = fmaf(cost, (float)NN, EPSF);   // S9 = NN exactly (e==1)
        float S2 = cost * T9 / D1;
        float bw = fminf(cost / (S2 + EPSF), 1.f);
        float cc9 = cost * bw / D1;
        float a0 = cc9, a1 = cc9 * Lc.w, a2 = cc9 * Lc.x, a3 = cc9 * Lc.y, a4 = cc9 * Lc.z;
#pragma unroll
        for (int o = 32; o > 0; o >>= 1) {
            a0 += __shfl_down(a0, o, 64); a1 += __shfl_down(a1, o, 64);
            a2 += __shfl_down(a2, o, 64); a3 += __shfl_down(a3, o, 64);
            a4 += __shfl_down(a4, o, 64);
        }
        if ((t & 63) == 0) {
            atomicAdd(AUX + b * 8 + 1, a0); atomicAdd(AUX + b * 8 + 2, a1);
            atomicAdd(AUX + b * 8 + 3, a2); atomicAdd(AUX + b * 8 + 4, a3);
            atomicAdd(AUX + b * 8 + 5, a4);
        }
    }
    bbar(ctr + (size_t)(bar * BB + b) * CTRPAD); bar++;
    // (iii) rr9[n] = A*|p|^2 + B - 2 p.C ; out += sum cur9*rr9
    if (t < TILE) {
        float A = sysload(AUX + b * 8 + 1), Bv = sysload(AUX + b * 8 + 2);
        float Cx = sysload(AUX + b * 8 + 3), Cy = sysload(AUX + b * 8 + 4);
        float Cz = sysload(AUX + b * 8 + 5);
        float rr9 = fmaf(A, Pr.w, Bv) - 2.f * (Pr.x * Cx + Pr.y * Cy + Pr.z * Cz);
        outacc += cur * rr9;                 // round 9 result term
#pragma unroll
        for (int o = 32; o > 0; o >>= 1) outacc += __shfl_down(outacc, o, 64);
        if ((t & 63) == 0) s_red[t >> 6] = outacc;
    }
    __syncthreads();
    if (t == 0) atomicAdd(out, s_red[0] + s_red[1]);
}

extern "C" void kernel_launch(void* const* d_in, const int* in_sizes, int n_in,
                              void* d_out, int out_size, void* d_ws, size_t ws_size,
                              hipStream_t stream) {
    const float* preds  = (const float*)d_in[0];
    const float* labels = (const float*)d_in[1];
    float* out = (float*)d_out;
    float* ws  = (float*)d_ws;

    // zeroed region: S,T,RS,RR | AUX(BB*8) | ctr(NBAR*BB*CTRPAD ints)
    float* S   = ws;
    float* T   = ws + BN;
    float* RS  = ws + 2 * BN;
    float* RR  = ws + 3 * BN;
    float* AUX = ws + 4 * BN;
    int*   ctr = (int*)(ws + 4 * BN + BB * 8);
    size_t zfloats = 4 * (size_t)BN + BB * 8 + (size_t)NBAR * BB * CTRPAD;
    // unzeroed: packed inputs + block-private staging (written before read)
    float4* Prow = (float4*)(ws + zfloats);
    float4* Lcol = Prow + BN;
    float4* st4  = Lcol + BN;
    float*  st1  = (float*)(st4 + (size_t)GRIDB * TILE);

    hipMemsetAsync(d_out, 0, sizeof(float), stream);
    hipMemsetAsync(ws, 0, zfloats * sizeof(float), stream);
    prep<<<BN / 256, 256, 0, stream>>>(preds, labels, Prow, Lcol);
    emd_all<<<GRIDB, TPB, 0, stream>>>(Prow, Lcol, S, T, RS, RR, AUX, ctr,
                                       st4, st1, out);
}